// Round 6
// baseline (623.024 us; speedup 1.0000x reference)
//
#include <hip/hip_runtime.h>
#include <math.h>

#define BB 8
#define E  128
#define OO 256
#define HH 112
#define WW 112
#define HWP (HH*WW)   // 12544

typedef _Float16 f16;
typedef _Float16 half8 __attribute__((ext_vector_type(8)));
typedef float f32x4 __attribute__((ext_vector_type(4)));

// LDS octet swizzle (R4-verified: bank conflicts -> 0)
#define SWZ(q, c) ((((q) + ((c) >> 1)) & 3) * 8)

// ---------------- precompute 1: normalized f16 weights, layout [tap][o][ch]
__global__ __launch_bounds__(128)
void wnorm16_kernel(const float* __restrict__ wgt, f16* __restrict__ wn16) {
    int o = blockIdx.x;
    int c = threadIdx.x;
    const float* row = wgt + (size_t)o * 1152 + c * 9;
    float v[9];
    float ss = 0.f;
    #pragma unroll
    for (int tp = 0; tp < 9; ++tp) { v[tp] = row[tp]; ss = fmaf(v[tp], v[tp], ss); }
    ss += __shfl_xor(ss, 1);  ss += __shfl_xor(ss, 2);
    ss += __shfl_xor(ss, 4);  ss += __shfl_xor(ss, 8);
    ss += __shfl_xor(ss, 16); ss += __shfl_xor(ss, 32);
    __shared__ float r2[2];
    if ((c & 63) == 0) r2[c >> 6] = ss;
    __syncthreads();
    float inv = rsqrtf(fmaxf(r2[0] + r2[1], 1e-24f));
    #pragma unroll
    for (int tp = 0; tp < 9; ++tp)
        wn16[((size_t)tp * OO + o) * E + c] = (f16)(v[tp] * inv);
}

// ---------------- precompute 2: inverse patch norms pinv[b][h][w]
__global__ __launch_bounds__(256)
void pinv_kernel(const float* __restrict__ x, float* __restrict__ pinv) {
    int hp = blockIdx.x;   // 0..55
    int b  = blockIdx.y;   // 0..7
    int h0 = hp * 2;
    int t  = threadIdx.x;
    __shared__ float ssqR[4][114];

    for (int i = t; i < 4 * 114; i += 256) {
        int r = i / 114, c = i % 114;
        int gh = h0 - 1 + r;
        int gw = c - 1;
        float s = 0.f;
        if ((unsigned)gh < HH && (unsigned)gw < WW) {
            const float* xp = x + ((size_t)b * E) * HWP + gh * WW + gw;
            #pragma unroll 8
            for (int ch = 0; ch < E; ++ch) {
                float v = xp[(size_t)ch * HWP];
                s = fmaf(v, v, s);
            }
        }
        ssqR[r][c] = s;
    }
    __syncthreads();
    if (t < 224) {
        int dh = t / 112, w = t % 112;
        float S = 0.f;
        #pragma unroll
        for (int r = 0; r < 3; ++r)
            #pragma unroll
            for (int c = 0; c < 3; ++c)
                S += ssqR[dh + r][w + c];
        pinv[(size_t)b * HWP + (h0 + dh) * WW + w] = rsqrtf(fmaxf(S, 1e-24f));
    }
}

// ---------------- tier-1 main: pipelined MFMA kernel
// Block: 64 o x 2 h x 128 w; 4 waves; wave = 64o x 64px (m4 x n4, 16x16x32 f16).
// T14 split: x-loads for chunk c+1 issued before MFMA(c); cvt+LDS-write after.
// Weights load inline in write phase (L2-resident, short latency).
__global__ __launch_bounds__(256, 1)
void cossim_pipe(const float* __restrict__ x, const f16* __restrict__ wn16,
                 const float* __restrict__ pinv, float* __restrict__ out) {
    int hp = blockIdx.x;
    int oy = blockIdx.y;
    int b  = blockIdx.z;
    int h0 = hp * 2;
    int o0 = oy * 64;
    int t    = threadIdx.x;
    int lane = t & 63;
    int wv   = t >> 6;

    __shared__ f16 ws[9][64][32];
    __shared__ f16 xs[4][130][32];

    f32x4 zero4 = {0.f, 0.f, 0.f, 0.f};
    f32x4 acc[4][4];
    #pragma unroll
    for (int mi = 0; mi < 4; ++mi)
        #pragma unroll
        for (int ni = 0; ni < 4; ++ni) acc[mi][ni] = zero4;

    const int lr = lane & 15;
    const int ls = lane >> 4;

    const int wo = t >> 2, wq = t & 3;            // weights: o, octet
    const int colL = lane & 15, cq = lane >> 4;   // x: col sub-lane, c-octet

    float vv[9][8];   // x prefetch registers (72 VGPR)

#define LOADX(CH0)                                                              \
    {                                                                           \
        _Pragma("unroll")                                                       \
        for (int it = 0; it < 9; ++it) {                                        \
            int g = it * 4 + wv;                                                \
            int r = g / 9, colb = g % 9;                                        \
            int cs = colb * 16 + colL;                                          \
            int gh = h0 - 1 + r;                                                \
            int gw = cs - 1;                                                    \
            bool ok = (cs < 130) && ((unsigned)gh < HH) && ((unsigned)gw < WW); \
            const float* xp = x + ((size_t)b * E + (CH0) + cq * 8) * HWP        \
                              + gh * WW + gw;                                   \
            _Pragma("unroll")                                                   \
            for (int e = 0; e < 8; ++e)                                         \
                vv[it][e] = ok ? xp[e * HWP] : 0.f;                             \
        }                                                                       \
    }

#define STAGEW(CH0)                                                             \
    {                                                                           \
        _Pragma("unroll")                                                       \
        for (int r = 0; r < 9; ++r) {                                           \
            half8 v = *(const half8*)(wn16 +                                    \
                ((size_t)(r * OO + o0 + wo)) * E + (CH0) + wq * 8);             \
            *(half8*)&ws[r][wo][SWZ(wq, wo)] = v;                               \
        }                                                                       \
    }

#define WRITEX()                                                                \
    {                                                                           \
        _Pragma("unroll")                                                       \
        for (int it = 0; it < 9; ++it) {                                        \
            int g = it * 4 + wv;                                                \
            int r = g / 9, colb = g % 9;                                        \
            int cs = colb * 16 + colL;                                          \
            if (cs < 130) {                                                     \
                half8 pk;                                                       \
                _Pragma("unroll")                                               \
                for (int e = 0; e < 8; ++e) pk[e] = (f16)vv[it][e];             \
                *(half8*)&xs[r][cs][SWZ(cq, cs)] = pk;                          \
            }                                                                   \
        }                                                                       \
    }

#define MFMA()                                                                  \
    {                                                                           \
        __builtin_amdgcn_s_setprio(1);                                          \
        _Pragma("unroll")                                                       \
        for (int tap = 0; tap < 9; ++tap) {                                     \
            int kh = tap / 3, kw = tap % 3;                                     \
            half8 A[4], Bf[4];                                                  \
            _Pragma("unroll")                                                   \
            for (int mi = 0; mi < 4; ++mi) {                                    \
                int row = mi * 16 + lr;                                         \
                A[mi] = *(const half8*)&ws[tap][row][SWZ(ls, row)];             \
            }                                                                   \
            _Pragma("unroll")                                                   \
            for (int dh = 0; dh < 2; ++dh)                                      \
                _Pragma("unroll")                                               \
                for (int wsg = 0; wsg < 2; ++wsg) {                             \
                    int col = wv * 32 + wsg * 16 + lr + kw;                     \
                    Bf[dh*2 + wsg] =                                            \
                        *(const half8*)&xs[dh + kh][col][SWZ(ls, col)];         \
                }                                                               \
            _Pragma("unroll")                                                   \
            for (int mi = 0; mi < 4; ++mi)                                      \
                _Pragma("unroll")                                               \
                for (int ni = 0; ni < 4; ++ni)                                  \
                    acc[mi][ni] = __builtin_amdgcn_mfma_f32_16x16x32_f16(       \
                        A[mi], Bf[ni], acc[mi][ni], 0, 0, 0);                   \
        }                                                                       \
        __builtin_amdgcn_s_setprio(0);                                          \
    }

    LOADX(0);
    STAGEW(0);
    WRITEX();
    __syncthreads();

    LOADX(32);
    MFMA();
    __syncthreads();
    STAGEW(32); WRITEX();
    __syncthreads();

    LOADX(64);
    MFMA();
    __syncthreads();
    STAGEW(64); WRITEX();
    __syncthreads();

    LOADX(96);
    MFMA();
    __syncthreads();
    STAGEW(96); WRITEX();
    __syncthreads();

    MFMA();

#undef LOADX
#undef STAGEW
#undef WRITEX
#undef MFMA

    // epilogue: scale by pinv only (weights pre-normalized)
    int lq = lane >> 4;
    #pragma unroll
    for (int ni = 0; ni < 4; ++ni) {
        int dh = ni >> 1, wsg = ni & 1;
        int w = wv * 32 + wsg * 16 + lr;
        if (w >= WW) continue;
        float pv = pinv[(size_t)b * HWP + (h0 + dh) * WW + w];
        int h = h0 + dh;
        #pragma unroll
        for (int mi = 0; mi < 4; ++mi) {
            #pragma unroll
            for (int rg = 0; rg < 4; ++rg) {
                int row = lq * 4 + rg;
                out[((size_t)(b * OO + o0 + mi*16 + row)) * HWP + h * WW + w]
                    = acc[mi][ni][rg] * pv;
            }
        }
    }
}

// ---------------- fallback (R4-proven) main kernel
template<int FAST>
__global__ __launch_bounds__(256, 2)
void cossim_mfma(const float* __restrict__ x, const float* __restrict__ wgt,
                 const f16* __restrict__ wn16, float* __restrict__ out) {
    int hp = blockIdx.x;
    int oy = blockIdx.y;
    int b  = blockIdx.z;
    int h0 = hp * 2;
    int o0 = oy * 64;
    int t    = threadIdx.x;
    int lane = t & 63;
    int wv   = t >> 6;

    __shared__ f16   ws[9][64][32];
    __shared__ f16   xs[4][130][32];
    __shared__ float ssqAcc[4][130];
    __shared__ float wSsq[64];
    __shared__ float pinvL[2][128];
    __shared__ float winv[64];

    for (int i = t; i < 4*130 + 64; i += 256) {
        if (i < 4*130) ((float*)ssqAcc)[i] = 0.f;
        else wSsq[i - 4*130] = 0.f;
    }
    __syncthreads();

    f32x4 zero4 = {0.f, 0.f, 0.f, 0.f};
    f32x4 acc[4][4];
    #pragma unroll
    for (int mi = 0; mi < 4; ++mi)
        #pragma unroll
        for (int ni = 0; ni < 4; ++ni) acc[mi][ni] = zero4;

    const int lr = lane & 15;
    const int ls = lane >> 4;

    for (int ch0 = 0; ch0 < E; ch0 += 32) {
        if (FAST) {
            int o = t >> 2, q = t & 3;
            #pragma unroll
            for (int r = 0; r < 9; ++r) {
                half8 v = *(const half8*)(wn16 + ((size_t)(r * OO + o0 + o)) * E + ch0 + q * 8);
                *(half8*)&ws[r][o][SWZ(q, o)] = v;
            }
        } else {
            int o = t >> 2, q = t & 3;
            const float* wrow = wgt + (size_t)(o0 + o) * 1152 + ch0 * 9 + q * 72;
            float v[72];
            float ss = 0.f;
            #pragma unroll
            for (int i = 0; i < 18; ++i) {
                float4 f = ((const float4*)wrow)[i];
                v[i*4+0] = f.x; v[i*4+1] = f.y; v[i*4+2] = f.z; v[i*4+3] = f.w;
                ss = fmaf(f.x, f.x, ss); ss = fmaf(f.y, f.y, ss);
                ss = fmaf(f.z, f.z, ss); ss = fmaf(f.w, f.w, ss);
            }
            #pragma unroll
            for (int tp = 0; tp < 9; ++tp) {
                half8 pk;
                #pragma unroll
                for (int cl = 0; cl < 8; ++cl) pk[cl] = (f16)v[cl*9 + tp];
                *(half8*)&ws[tp][o][SWZ(q, o)] = pk;
            }
            ss += __shfl_xor(ss, 1);
            ss += __shfl_xor(ss, 2);
            if (q == 0) wSsq[o] += ss;
        }
        {
            int colL = lane & 15, cq = lane >> 4;
            #pragma unroll 2
            for (int it = 0; it < 9; ++it) {
                int g = it * 4 + wv;
                int r = g / 9, colb = g % 9;
                int cs = colb * 16 + colL;
                int gh = h0 - 1 + r;
                int gw = cs - 1;
                bool okc = (cs < 130);
                bool ok  = okc && ((unsigned)gh < HH) && ((unsigned)gw < WW);
                const float* xp = x + ((size_t)b * E + ch0 + cq * 8) * HWP + gh * WW + gw;
                float vv[8];
                float ss = 0.f;
                #pragma unroll
                for (int e = 0; e < 8; ++e) {
                    float v = ok ? xp[e * HWP] : 0.f;
                    vv[e] = v;
                    ss = fmaf(v, v, ss);
                }
                if (okc) {
                    half8 pk;
                    #pragma unroll
                    for (int e = 0; e < 8; ++e) pk[e] = (f16)vv[e];
                    *(half8*)&xs[r][cs][SWZ(cq, cs)] = pk;
                }
                ss += __shfl_xor(ss, 16);
                ss += __shfl_xor(ss, 32);
                if (cq == 0 && okc) ssqAcc[r][cs] += ss;
            }
        }
        __syncthreads();

        __builtin_amdgcn_s_setprio(1);
        #pragma unroll
        for (int tap = 0; tap < 9; ++tap) {
            int kh = tap / 3, kw = tap % 3;
            half8 A[4], Bf[4];
            #pragma unroll
            for (int mi = 0; mi < 4; ++mi) {
                int row = mi * 16 + lr;
                A[mi] = *(const half8*)&ws[tap][row][SWZ(ls, row)];
            }
            #pragma unroll
            for (int dh = 0; dh < 2; ++dh)
                #pragma unroll
                for (int wsg = 0; wsg < 2; ++wsg) {
                    int col = wv * 32 + wsg * 16 + lr + kw;
                    Bf[dh*2 + wsg] = *(const half8*)&xs[dh + kh][col][SWZ(ls, col)];
                }
            #pragma unroll
            for (int mi = 0; mi < 4; ++mi)
                #pragma unroll
                for (int ni = 0; ni < 4; ++ni)
                    acc[mi][ni] = __builtin_amdgcn_mfma_f32_16x16x32_f16(
                        A[mi], Bf[ni], acc[mi][ni], 0, 0, 0);
        }
        __builtin_amdgcn_s_setprio(0);
        __syncthreads();
    }

    if (!FAST && t < 64) winv[t] = rsqrtf(fmaxf(wSsq[t], 1e-24f));
    {
        int dh = t >> 7, w = t & 127;
        float S = 0.f;
        #pragma unroll
        for (int r = 0; r < 3; ++r)
            #pragma unroll
            for (int c = 0; c < 3; ++c)
                S += ssqAcc[dh + r][w + c];
        pinvL[dh][w] = rsqrtf(fmaxf(S, 1e-24f));
    }
    __syncthreads();

    int lq = lane >> 4;
    #pragma unroll
    for (int ni = 0; ni < 4; ++ni) {
        int dh = ni >> 1, wsg = ni & 1;
        int w = wv * 32 + wsg * 16 + lr;
        if (w >= WW) continue;
        float pv = pinvL[dh][w];
        int h = h0 + dh;
        #pragma unroll
        for (int mi = 0; mi < 4; ++mi) {
            #pragma unroll
            for (int rg = 0; rg < 4; ++rg) {
                int row = lq * 4 + rg;
                float s = acc[mi][ni][rg] * pv;
                if (!FAST) s *= winv[mi*16 + row];
                out[((size_t)(b * OO + o0 + mi*16 + row)) * HWP + h * WW + w] = s;
            }
        }
    }
}

extern "C" void kernel_launch(void* const* d_in, const int* in_sizes, int n_in,
                              void* d_out, int out_size, void* d_ws, size_t ws_size,
                              hipStream_t stream) {
    const float* x   = (const float*)d_in[0];
    const float* wgt = (const float*)d_in[1];
    float* out = (float*)d_out;

    const size_t pinv_bytes = (size_t)BB * HWP * sizeof(float);      // 401408
    const size_t wn_bytes   = (size_t)9 * OO * E * sizeof(f16);      // 589824
    if (ws_size >= pinv_bytes + wn_bytes && d_ws != nullptr) {
        float* pinv = (float*)d_ws;
        f16*   wn16 = (f16*)((char*)d_ws + pinv_bytes);
        wnorm16_kernel<<<OO, 128, 0, stream>>>(wgt, wn16);
        pinv_kernel<<<dim3(56, BB), 256, 0, stream>>>(x, pinv);
        cossim_pipe<<<dim3(56, 4, BB), 256, 0, stream>>>(x, wn16, pinv, out);
    } else if (ws_size >= wn_bytes && d_ws != nullptr) {
        f16* wn16 = (f16*)d_ws;
        wnorm16_kernel<<<OO, 128, 0, stream>>>(wgt, wn16);
        cossim_mfma<1><<<dim3(56, 4, BB), 256, 0, stream>>>(x, wgt, wn16, out);
    } else {
        cossim_mfma<0><<<dim3(56, 4, BB), 256, 0, stream>>>(x, wgt, nullptr, out);
    }
}

// Round 7
// 211.417 us; speedup vs baseline: 2.9469x; 2.9469x over previous
//
#include <hip/hip_runtime.h>
#include <math.h>

#define BB 8
#define E  128
#define OO 256
#define HH 112
#define WW 112
#define HWP (HH*WW)   // 12544

typedef _Float16 f16;
typedef _Float16 half8 __attribute__((ext_vector_type(8)));
typedef float f32x4 __attribute__((ext_vector_type(4)));

// LDS octet swizzle (R4-verified: bank conflicts -> 0)
#define SWZ(q, c) ((((q) + ((c) >> 1)) & 3) * 8)

// ---------------- precompute 1: normalized f16 weights, layout [tap][o][ch]
__global__ __launch_bounds__(128)
void wnorm16_kernel(const float* __restrict__ wgt, f16* __restrict__ wn16) {
    int o = blockIdx.x;
    int c = threadIdx.x;
    const float* row = wgt + (size_t)o * 1152 + c * 9;
    float v[9];
    float ss = 0.f;
    #pragma unroll
    for (int tp = 0; tp < 9; ++tp) { v[tp] = row[tp]; ss = fmaf(v[tp], v[tp], ss); }
    ss += __shfl_xor(ss, 1);  ss += __shfl_xor(ss, 2);
    ss += __shfl_xor(ss, 4);  ss += __shfl_xor(ss, 8);
    ss += __shfl_xor(ss, 16); ss += __shfl_xor(ss, 32);
    __shared__ float r2[2];
    if ((c & 63) == 0) r2[c >> 6] = ss;
    __syncthreads();
    float inv = rsqrtf(fmaxf(r2[0] + r2[1], 1e-24f));
    #pragma unroll
    for (int tp = 0; tp < 9; ++tp)
        wn16[((size_t)tp * OO + o) * E + c] = (f16)(v[tp] * inv);
}

// ---------------- precompute 2: inverse patch norms pinv[b][h][w]
__global__ __launch_bounds__(256)
void pinv_kernel(const float* __restrict__ x, float* __restrict__ pinv) {
    int hp = blockIdx.x;   // 0..55
    int b  = blockIdx.y;   // 0..7
    int h0 = hp * 2;
    int t  = threadIdx.x;
    __shared__ float ssqR[4][114];

    for (int i = t; i < 4 * 114; i += 256) {
        int r = i / 114, c = i % 114;
        int gh = h0 - 1 + r;
        int gw = c - 1;
        float s = 0.f;
        if ((unsigned)gh < HH && (unsigned)gw < WW) {
            const float* xp = x + ((size_t)b * E) * HWP + gh * WW + gw;
            #pragma unroll 8
            for (int ch = 0; ch < E; ++ch) {
                float v = xp[(size_t)ch * HWP];
                s = fmaf(v, v, s);
            }
        }
        ssqR[r][c] = s;
    }
    __syncthreads();
    if (t < 224) {
        int dh = t / 112, w = t % 112;
        float S = 0.f;
        #pragma unroll
        for (int r = 0; r < 3; ++r)
            #pragma unroll
            for (int c = 0; c < 3; ++c)
                S += ssqR[dh + r][w + c];
        pinv[(size_t)b * HWP + (h0 + dh) * WW + w] = rsqrtf(fmaxf(S, 1e-24f));
    }
}

// ---------------- tier-1 main: R4 serial structure + fast x-staging
// Block: 64 o x 2 h x 128 w; 4 waves; wave = 64o x 64px (m4 x n4, 16x16x32 f16).
// x staged via aligned float4 loads + 4x4 u32 quad transpose -> b128 LDS writes.
__global__ __launch_bounds__(256, 2)
void cossim_fast(const float* __restrict__ x, const f16* __restrict__ wn16,
                 const float* __restrict__ pinv, float* __restrict__ out) {
    int hp = blockIdx.x;
    int oy = blockIdx.y;
    int b  = blockIdx.z;
    int h0 = hp * 2;
    int o0 = oy * 64;
    int t    = threadIdx.x;
    int lane = t & 63;
    int wv   = t >> 6;

    __shared__ f16 ws[9][64][32];
    __shared__ f16 xs[4][130][32];

    // zero the never-staged halo stripes once: cs==0 and cs 113..129
    for (int i = t; i < 4 * 18 * 16; i += 256) {
        int r = i / 288, rem = i % 288;
        int csi = rem >> 4, pr = rem & 15;
        int cs = (csi == 0) ? 0 : 112 + csi;
        *(unsigned int*)&xs[r][cs][pr * 2] = 0u;
    }

    f32x4 zero4 = {0.f, 0.f, 0.f, 0.f};
    f32x4 acc[4][4];
    #pragma unroll
    for (int mi = 0; mi < 4; ++mi)
        #pragma unroll
        for (int ni = 0; ni < 4; ++ni) acc[mi][ni] = zero4;

    const int lr = lane & 15;
    const int ls = lane >> 4;
    const int qp = t & 3;      // quad lane (also ws octet role)
    const int qi = t >> 2;     // quad index 0..63 (also ws o role)

    for (int ch0 = 0; ch0 < E; ch0 += 32) {
        // ---- stage W: 9 half8 L2 loads + swizzled b128 writes (R4-proven)
        #pragma unroll
        for (int r = 0; r < 9; ++r) {
            half8 v = *(const half8*)(wn16 + ((size_t)(r * OO + o0 + qi)) * E + ch0 + qp * 8);
            *(half8*)&ws[r][qi][SWZ(qp, qi)] = v;
        }

        // ---- stage X: 7 iters/thread; quad handles (r, cq) x 4 cols x 8 ch
        #pragma unroll
        for (int it = 0; it < 7; ++it) {
            int gi   = it * 64 + qi;      // 0..447
            int cg   = gi % 28;           // col-quad: gw0 = 4*cg (aligned)
            int rest = gi / 28;           // 0..15
            int cq   = rest & 3;          // channel octet
            int r    = rest >> 2;         // row 0..3
            int gh   = h0 - 1 + r;
            bool ok  = ((unsigned)gh < HH);
            int ch   = ch0 + cq * 8 + qp * 2;
            const float* xp = x + ((size_t)b * E + ch) * HWP + (ok ? gh : 0) * WW + cg * 4;
            float4 va = ok ? *(const float4*)xp         : *(const float4*)&zero4;
            float4 vb = ok ? *(const float4*)(xp + HWP) : *(const float4*)&zero4;

            // pack per-col channel pairs (lo = even ch)
            unsigned int M[4];
            {
                union { struct { f16 lo, hi; } h; unsigned int u; } pk_;
                pk_.h.lo = (f16)va.x; pk_.h.hi = (f16)vb.x; M[0] = pk_.u;
                pk_.h.lo = (f16)va.y; pk_.h.hi = (f16)vb.y; M[1] = pk_.u;
                pk_.h.lo = (f16)va.z; pk_.h.hi = (f16)vb.z; M[2] = pk_.u;
                pk_.h.lo = (f16)va.w; pk_.h.hi = (f16)vb.w; M[3] = pk_.u;
            }
            // 4x4 u32 transpose within the quad (hand-verified):
            bool bs = (qp & 2) != 0;
            unsigned int s0 = __shfl_xor(bs ? M[0] : M[2], 2);
            unsigned int s1 = __shfl_xor(bs ? M[1] : M[3], 2);
            unsigned int b0 = bs ? s0 : M[0];
            unsigned int b1 = bs ? s1 : M[1];
            unsigned int b2 = bs ? M[2] : s0;
            unsigned int b3 = bs ? M[3] : s1;
            bool lsel = (qp & 1) != 0;
            unsigned int u0 = __shfl_xor(lsel ? b0 : b1, 1);
            unsigned int u1 = __shfl_xor(lsel ? b2 : b3, 1);
            uint4 Y;
            Y.x = lsel ? u0 : b0;
            Y.y = lsel ? b1 : u0;
            Y.z = lsel ? u1 : b2;
            Y.w = lsel ? b3 : u1;

            int cs = cg * 4 + 1 + qp;     // 1..112, always in-image
            *(uint4*)&xs[r][cs][SWZ(cq, cs)] = Y;
        }
        __syncthreads();

        // ---- MFMA (R4-proven)
        __builtin_amdgcn_s_setprio(1);
        #pragma unroll
        for (int tap = 0; tap < 9; ++tap) {
            int kh = tap / 3, kw = tap % 3;
            half8 A[4], Bf[4];
            #pragma unroll
            for (int mi = 0; mi < 4; ++mi) {
                int row = mi * 16 + lr;
                A[mi] = *(const half8*)&ws[tap][row][SWZ(ls, row)];
            }
            #pragma unroll
            for (int dh = 0; dh < 2; ++dh)
                #pragma unroll
                for (int wsg = 0; wsg < 2; ++wsg) {
                    int col = wv * 32 + wsg * 16 + lr + kw;
                    Bf[dh*2 + wsg] = *(const half8*)&xs[dh + kh][col][SWZ(ls, col)];
                }
            #pragma unroll
            for (int mi = 0; mi < 4; ++mi)
                #pragma unroll
                for (int ni = 0; ni < 4; ++ni)
                    acc[mi][ni] = __builtin_amdgcn_mfma_f32_16x16x32_f16(
                        A[mi], Bf[ni], acc[mi][ni], 0, 0, 0);
        }
        __builtin_amdgcn_s_setprio(0);
        __syncthreads();
    }

    // ---- epilogue: scale by pinv (weights pre-normalized)
    int lq = lane >> 4;
    #pragma unroll
    for (int ni = 0; ni < 4; ++ni) {
        int dh = ni >> 1, wsg = ni & 1;
        int w = wv * 32 + wsg * 16 + lr;
        if (w >= WW) continue;
        float pv = pinv[(size_t)b * HWP + (h0 + dh) * WW + w];
        int h = h0 + dh;
        #pragma unroll
        for (int mi = 0; mi < 4; ++mi) {
            #pragma unroll
            for (int rg = 0; rg < 4; ++rg) {
                int row = lq * 4 + rg;
                out[((size_t)(b * OO + o0 + mi*16 + row)) * HWP + h * WW + w]
                    = acc[mi][ni][rg] * pv;
            }
        }
    }
}

// ---------------- fallback (R4-proven) main kernel
template<int FAST>
__global__ __launch_bounds__(256, 2)
void cossim_mfma(const float* __restrict__ x, const float* __restrict__ wgt,
                 const f16* __restrict__ wn16, float* __restrict__ out) {
    int hp = blockIdx.x;
    int oy = blockIdx.y;
    int b  = blockIdx.z;
    int h0 = hp * 2;
    int o0 = oy * 64;
    int t    = threadIdx.x;
    int lane = t & 63;
    int wv   = t >> 6;

    __shared__ f16   ws[9][64][32];
    __shared__ f16   xs[4][130][32];
    __shared__ float ssqAcc[4][130];
    __shared__ float wSsq[64];
    __shared__ float pinvL[2][128];
    __shared__ float winv[64];

    for (int i = t; i < 4*130 + 64; i += 256) {
        if (i < 4*130) ((float*)ssqAcc)[i] = 0.f;
        else wSsq[i - 4*130] = 0.f;
    }
    __syncthreads();

    f32x4 zero4 = {0.f, 0.f, 0.f, 0.f};
    f32x4 acc[4][4];
    #pragma unroll
    for (int mi = 0; mi < 4; ++mi)
        #pragma unroll
        for (int ni = 0; ni < 4; ++ni) acc[mi][ni] = zero4;

    const int lr = lane & 15;
    const int ls = lane >> 4;

    for (int ch0 = 0; ch0 < E; ch0 += 32) {
        if (FAST) {
            int o = t >> 2, q = t & 3;
            #pragma unroll
            for (int r = 0; r < 9; ++r) {
                half8 v = *(const half8*)(wn16 + ((size_t)(r * OO + o0 + o)) * E + ch0 + q * 8);
                *(half8*)&ws[r][o][SWZ(q, o)] = v;
            }
        } else {
            int o = t >> 2, q = t & 3;
            const float* wrow = wgt + (size_t)(o0 + o) * 1152 + ch0 * 9 + q * 72;
            float v[72];
            float ss = 0.f;
            #pragma unroll
            for (int i = 0; i < 18; ++i) {
                float4 f = ((const float4*)wrow)[i];
                v[i*4+0] = f.x; v[i*4+1] = f.y; v[i*4+2] = f.z; v[i*4+3] = f.w;
                ss = fmaf(f.x, f.x, ss); ss = fmaf(f.y, f.y, ss);
                ss = fmaf(f.z, f.z, ss); ss = fmaf(f.w, f.w, ss);
            }
            #pragma unroll
            for (int tp = 0; tp < 9; ++tp) {
                half8 pk;
                #pragma unroll
                for (int cl = 0; cl < 8; ++cl) pk[cl] = (f16)v[cl*9 + tp];
                *(half8*)&ws[tp][o][SWZ(q, o)] = pk;
            }
            ss += __shfl_xor(ss, 1);
            ss += __shfl_xor(ss, 2);
            if (q == 0) wSsq[o] += ss;
        }
        {
            int colL = lane & 15, cq = lane >> 4;
            #pragma unroll 2
            for (int it = 0; it < 9; ++it) {
                int g = it * 4 + wv;
                int r = g / 9, colb = g % 9;
                int cs = colb * 16 + colL;
                int gh = h0 - 1 + r;
                int gw = cs - 1;
                bool okc = (cs < 130);
                bool ok  = okc && ((unsigned)gh < HH) && ((unsigned)gw < WW);
                const float* xp = x + ((size_t)b * E + ch0 + cq * 8) * HWP + gh * WW + gw;
                float vv[8];
                float ss = 0.f;
                #pragma unroll
                for (int e = 0; e < 8; ++e) {
                    float v = ok ? xp[e * HWP] : 0.f;
                    vv[e] = v;
                    ss = fmaf(v, v, ss);
                }
                if (okc) {
                    half8 pk;
                    #pragma unroll
                    for (int e = 0; e < 8; ++e) pk[e] = (f16)vv[e];
                    *(half8*)&xs[r][cs][SWZ(cq, cs)] = pk;
                }
                ss += __shfl_xor(ss, 16);
                ss += __shfl_xor(ss, 32);
                if (cq == 0 && okc) ssqAcc[r][cs] += ss;
            }
        }
        __syncthreads();

        __builtin_amdgcn_s_setprio(1);
        #pragma unroll
        for (int tap = 0; tap < 9; ++tap) {
            int kh = tap / 3, kw = tap % 3;
            half8 A[4], Bf[4];
            #pragma unroll
            for (int mi = 0; mi < 4; ++mi) {
                int row = mi * 16 + lr;
                A[mi] = *(const half8*)&ws[tap][row][SWZ(ls, row)];
            }
            #pragma unroll
            for (int dh = 0; dh < 2; ++dh)
                #pragma unroll
                for (int wsg = 0; wsg < 2; ++wsg) {
                    int col = wv * 32 + wsg * 16 + lr + kw;
                    Bf[dh*2 + wsg] = *(const half8*)&xs[dh + kh][col][SWZ(ls, col)];
                }
            #pragma unroll
            for (int mi = 0; mi < 4; ++mi)
                #pragma unroll
                for (int ni = 0; ni < 4; ++ni)
                    acc[mi][ni] = __builtin_amdgcn_mfma_f32_16x16x32_f16(
                        A[mi], Bf[ni], acc[mi][ni], 0, 0, 0);
        }
        __builtin_amdgcn_s_setprio(0);
        __syncthreads();
    }

    if (!FAST && t < 64) winv[t] = rsqrtf(fmaxf(wSsq[t], 1e-24f));
    {
        int dh = t >> 7, w = t & 127;
        float S = 0.f;
        #pragma unroll
        for (int r = 0; r < 3; ++r)
            #pragma unroll
            for (int c = 0; c < 3; ++c)
                S += ssqAcc[dh + r][w + c];
        pinvL[dh][w] = rsqrtf(fmaxf(S, 1e-24f));
    }
    __syncthreads();

    int lq = lane >> 4;
    #pragma unroll
    for (int ni = 0; ni < 4; ++ni) {
        int dh = ni >> 1, wsg = ni & 1;
        int w = wv * 32 + wsg * 16 + lr;
        if (w >= WW) continue;
        float pv = pinvL[dh][w];
        int h = h0 + dh;
        #pragma unroll
        for (int mi = 0; mi < 4; ++mi) {
            #pragma unroll
            for (int rg = 0; rg < 4; ++rg) {
                int row = lq * 4 + rg;
                float s = acc[mi][ni][rg] * pv;
                if (!FAST) s *= winv[mi*16 + row];
                out[((size_t)(b * OO + o0 + mi*16 + row)) * HWP + h * WW + w] = s;
            }
        }
    }
}

extern "C" void kernel_launch(void* const* d_in, const int* in_sizes, int n_in,
                              void* d_out, int out_size, void* d_ws, size_t ws_size,
                              hipStream_t stream) {
    const float* x   = (const float*)d_in[0];
    const float* wgt = (const float*)d_in[1];
    float* out = (float*)d_out;

    const size_t pinv_bytes = (size_t)BB * HWP * sizeof(float);      // 401408
    const size_t wn_bytes   = (size_t)9 * OO * E * sizeof(f16);      // 589824
    if (ws_size >= pinv_bytes + wn_bytes && d_ws != nullptr) {
        float* pinv = (float*)d_ws;
        f16*   wn16 = (f16*)((char*)d_ws + pinv_bytes);
        wnorm16_kernel<<<OO, 128, 0, stream>>>(wgt, wn16);
        pinv_kernel<<<dim3(56, BB), 256, 0, stream>>>(x, pinv);
        cossim_fast<<<dim3(56, 4, BB), 256, 0, stream>>>(x, wn16, pinv, out);
    } else if (ws_size >= wn_bytes && d_ws != nullptr) {
        f16* wn16 = (f16*)d_ws;
        wnorm16_kernel<<<OO, 128, 0, stream>>>(wgt, wn16);
        cossim_mfma<1><<<dim3(56, 4, BB), 256, 0, stream>>>(x, wgt, wn16, out);
    } else {
        cossim_mfma<0><<<dim3(56, 4, BB), 256, 0, stream>>>(x, wgt, nullptr, out);
    }
}

// Round 8
// 205.567 us; speedup vs baseline: 3.0308x; 1.0285x over previous
//
#include <hip/hip_runtime.h>
#include <math.h>

#define BB 8
#define E  128
#define OO 256
#define HH 112
#define WW 112
#define HWP (HH*WW)   // 12544

typedef _Float16 f16;
typedef _Float16 half8 __attribute__((ext_vector_type(8)));
typedef float f32x4 __attribute__((ext_vector_type(4)));

// R4-proven swizzle for 64B-stride (32 f16) rows
#define SWZ(q, c) ((((q) + ((c) >> 1)) & 3) * 8)
// New swizzle for 32B-stride (16 f16) rows: 2 octets, xor by (idx>>2)&1.
// Per-16-lane b128 read pattern => every bank-quad hit exactly 2x (free).
#define SWZ16(oct, idx) ((((oct) ^ (((idx) >> 2) & 1))) * 8)

// ---------------- precompute 1: normalized f16 weights, layout [tap][o][ch]
__global__ __launch_bounds__(128)
void wnorm16_kernel(const float* __restrict__ wgt, f16* __restrict__ wn16) {
    int o = blockIdx.x;
    int c = threadIdx.x;
    const float* row = wgt + (size_t)o * 1152 + c * 9;
    float v[9];
    float ss = 0.f;
    #pragma unroll
    for (int tp = 0; tp < 9; ++tp) { v[tp] = row[tp]; ss = fmaf(v[tp], v[tp], ss); }
    ss += __shfl_xor(ss, 1);  ss += __shfl_xor(ss, 2);
    ss += __shfl_xor(ss, 4);  ss += __shfl_xor(ss, 8);
    ss += __shfl_xor(ss, 16); ss += __shfl_xor(ss, 32);
    __shared__ float r2[2];
    if ((c & 63) == 0) r2[c >> 6] = ss;
    __syncthreads();
    float inv = rsqrtf(fmaxf(r2[0] + r2[1], 1e-24f));
    #pragma unroll
    for (int tp = 0; tp < 9; ++tp)
        wn16[((size_t)tp * OO + o) * E + c] = (f16)(v[tp] * inv);
}

// ---------------- precompute 2: inverse patch norms pinv[b][h][w]
__global__ __launch_bounds__(256)
void pinv_kernel(const float* __restrict__ x, float* __restrict__ pinv) {
    int hp = blockIdx.x;   // 0..55
    int b  = blockIdx.y;   // 0..7
    int h0 = hp * 2;
    int t  = threadIdx.x;
    __shared__ float ssqR[4][114];

    for (int i = t; i < 4 * 114; i += 256) {
        int r = i / 114, c = i % 114;
        int gh = h0 - 1 + r;
        int gw = c - 1;
        float s = 0.f;
        if ((unsigned)gh < HH && (unsigned)gw < WW) {
            const float* xp = x + ((size_t)b * E) * HWP + gh * WW + gw;
            #pragma unroll 8
            for (int ch = 0; ch < E; ++ch) {
                float v = xp[(size_t)ch * HWP];
                s = fmaf(v, v, s);
            }
        }
        ssqR[r][c] = s;
    }
    __syncthreads();
    if (t < 224) {
        int dh = t / 112, w = t % 112;
        float S = 0.f;
        #pragma unroll
        for (int r = 0; r < 3; ++r)
            #pragma unroll
            for (int c = 0; c < 3; ++c)
                S += ssqR[dh + r][w + c];
        pinv[(size_t)b * HWP + (h0 + dh) * WW + w] = rsqrtf(fmaxf(S, 1e-24f));
    }
}

// ---------------- tier-1 main: 16-ch chunks, tap-paired K=32, 4 blocks/CU
// Block: 64 o x 2 h x 128 w; 4 waves; wave = 64o x (2h x 32w) px (m4 x n4).
// K of each mfma = [tap_a ch0..15 | tap_b ch0..15]; lane ls picks tap 2p+(ls>>1),
// octet ls&1. 9 taps -> 4 real pairs + (tap8, zero-pad tap9).
__global__ __launch_bounds__(256, 4)
void cossim_cc16(const float* __restrict__ x, const f16* __restrict__ wn16,
                 const float* __restrict__ pinv, float* __restrict__ out) {
    // XCD-aware 1-D grid decode: round-robin XCD = bid&7 -> one batch per XCD
    int bid = blockIdx.x;        // 0..1791
    int b   = bid & 7;
    int j   = bid >> 3;          // 0..223
    int oy  = j / 56;
    int hp  = j % 56;
    int h0 = hp * 2;
    int o0 = oy * 64;
    int t    = threadIdx.x;
    int lane = t & 63;
    int wv   = t >> 6;

    __shared__ f16 ws[10][64][16];   // taps 0..8 staged; tap 9 stays zero
    __shared__ f16 xs[4][130][16];

    // zero pad-tap 9 once (never re-written)
    if (t < 128) {
        int o = t >> 1, oct = t & 1;
        *(half8*)&ws[9][o][oct * 8] = (half8)(f16)0.f;
    }

    f32x4 zero4 = {0.f, 0.f, 0.f, 0.f};
    f32x4 acc[4][4];
    #pragma unroll
    for (int mi = 0; mi < 4; ++mi)
        #pragma unroll
        for (int ni = 0; ni < 4; ++ni) acc[mi][ni] = zero4;

    const int lr = lane & 15;
    const int ls = lane >> 4;

    for (int ch0 = 0; ch0 < E; ch0 += 16) {
        // ---- stage W: 9 taps x 64 o x 2 octets = 1152 half8 copies
        #pragma unroll
        for (int k = 0; k < 5; ++k) {
            int i = t + k * 256;
            if (i < 1152) {
                int tap = i >> 7, rem = i & 127, o = rem >> 1, oct = rem & 1;
                half8 v = *(const half8*)(wn16 +
                    ((size_t)(tap * OO + o0 + o)) * E + ch0 + oct * 8);
                *(half8*)&ws[tap][o][SWZ16(oct, o)] = v;
            }
        }
        // ---- stage X: 4 rows x 130 cols x 2 octets = 1040 half8s (scalar f32 loads)
        #pragma unroll
        for (int k = 0; k < 5; ++k) {
            int i = t + k * 256;
            if (i < 1040) {
                int r = i / 260, rem = i % 260, cs = rem >> 1, oct = rem & 1;
                int gh = h0 - 1 + r, gw = cs - 1;
                bool ok = ((unsigned)gh < HH) && ((unsigned)gw < WW);
                const float* xp = x + ((size_t)b * E + ch0 + oct * 8) * HWP
                                  + gh * WW + gw;
                half8 pk;
                #pragma unroll
                for (int e = 0; e < 8; ++e)
                    pk[e] = ok ? (f16)xp[e * HWP] : (f16)0.f;
                *(half8*)&xs[r][cs][SWZ16(oct, cs)] = pk;
            }
        }
        __syncthreads();

        // ---- MFMA: 5 tap-pairs x 16 mfma
        __builtin_amdgcn_s_setprio(1);
        #pragma unroll
        for (int p = 0; p < 5; ++p) {
            int tpl = 2 * p + (ls >> 1);        // my k-slice's logical tap (<=9)
            int tpe = (tpl > 8) ? 0 : tpl;      // clamp pad-tap for B addressing
            int kh  = tpe / 3;
            int kw  = tpe - 3 * kh;
            int oct = ls & 1;
            half8 A[4], Bf[4];
            #pragma unroll
            for (int mi = 0; mi < 4; ++mi) {
                int row = mi * 16 + lr;
                A[mi] = *(const half8*)&ws[tpl][row][SWZ16(oct, row)];
            }
            #pragma unroll
            for (int dh = 0; dh < 2; ++dh)
                #pragma unroll
                for (int wsg = 0; wsg < 2; ++wsg) {
                    int col = wv * 32 + wsg * 16 + lr + kw;
                    Bf[dh * 2 + wsg] = *(const half8*)&xs[dh + kh][col][SWZ16(oct, col)];
                }
            #pragma unroll
            for (int mi = 0; mi < 4; ++mi)
                #pragma unroll
                for (int ni = 0; ni < 4; ++ni)
                    acc[mi][ni] = __builtin_amdgcn_mfma_f32_16x16x32_f16(
                        A[mi], Bf[ni], acc[mi][ni], 0, 0, 0);
        }
        __builtin_amdgcn_s_setprio(0);
        __syncthreads();
    }

    // ---- epilogue: scale by pinv (weights pre-normalized)
    int lq = lane >> 4;
    #pragma unroll
    for (int ni = 0; ni < 4; ++ni) {
        int dh = ni >> 1, wsg = ni & 1;
        int w = wv * 32 + wsg * 16 + lr;
        if (w >= WW) continue;
        float pv = pinv[(size_t)b * HWP + (h0 + dh) * WW + w];
        int h = h0 + dh;
        #pragma unroll
        for (int mi = 0; mi < 4; ++mi) {
            #pragma unroll
            for (int rg = 0; rg < 4; ++rg) {
                int row = lq * 4 + rg;
                out[((size_t)(b * OO + o0 + mi * 16 + row)) * HWP + h * WW + w]
                    = acc[mi][ni][rg] * pv;
            }
        }
    }
}

// ---------------- fallback (R4-proven) main kernel
template<int FAST>
__global__ __launch_bounds__(256, 2)
void cossim_mfma(const float* __restrict__ x, const float* __restrict__ wgt,
                 const f16* __restrict__ wn16, float* __restrict__ out) {
    int hp = blockIdx.x;
    int oy = blockIdx.y;
    int b  = blockIdx.z;
    int h0 = hp * 2;
    int o0 = oy * 64;
    int t    = threadIdx.x;
    int lane = t & 63;
    int wv   = t >> 6;

    __shared__ f16   ws[9][64][32];
    __shared__ f16   xs[4][130][32];
    __shared__ float ssqAcc[4][130];
    __shared__ float wSsq[64];
    __shared__ float pinvL[2][128];
    __shared__ float winv[64];

    for (int i = t; i < 4*130 + 64; i += 256) {
        if (i < 4*130) ((float*)ssqAcc)[i] = 0.f;
        else wSsq[i - 4*130] = 0.f;
    }
    __syncthreads();

    f32x4 zero4 = {0.f, 0.f, 0.f, 0.f};
    f32x4 acc[4][4];
    #pragma unroll
    for (int mi = 0; mi < 4; ++mi)
        #pragma unroll
        for (int ni = 0; ni < 4; ++ni) acc[mi][ni] = zero4;

    const int lr = lane & 15;
    const int ls = lane >> 4;

    for (int ch0 = 0; ch0 < E; ch0 += 32) {
        if (FAST) {
            int o = t >> 2, q = t & 3;
            #pragma unroll
            for (int r = 0; r < 9; ++r) {
                half8 v = *(const half8*)(wn16 + ((size_t)(r * OO + o0 + o)) * E + ch0 + q * 8);
                *(half8*)&ws[r][o][SWZ(q, o)] = v;
            }
        } else {
            int o = t >> 2, q = t & 3;
            const float* wrow = wgt + (size_t)(o0 + o) * 1152 + ch0 * 9 + q * 72;
            float v[72];
            float ss = 0.f;
            #pragma unroll
            for (int i = 0; i < 18; ++i) {
                float4 f = ((const float4*)wrow)[i];
                v[i*4+0] = f.x; v[i*4+1] = f.y; v[i*4+2] = f.z; v[i*4+3] = f.w;
                ss = fmaf(f.x, f.x, ss); ss = fmaf(f.y, f.y, ss);
                ss = fmaf(f.z, f.z, ss); ss = fmaf(f.w, f.w, ss);
            }
            #pragma unroll
            for (int tp = 0; tp < 9; ++tp) {
                half8 pk;
                #pragma unroll
                for (int cl = 0; cl < 8; ++cl) pk[cl] = (f16)v[cl*9 + tp];
                *(half8*)&ws[tp][o][SWZ(q, o)] = pk;
            }
            ss += __shfl_xor(ss, 1);
            ss += __shfl_xor(ss, 2);
            if (q == 0) wSsq[o] += ss;
        }
        {
            int colL = lane & 15, cq = lane >> 4;
            #pragma unroll 2
            for (int it = 0; it < 9; ++it) {
                int g = it * 4 + wv;
                int r = g / 9, colb = g % 9;
                int cs = colb * 16 + colL;
                int gh = h0 - 1 + r;
                int gw = cs - 1;
                bool okc = (cs < 130);
                bool ok  = okc && ((unsigned)gh < HH) && ((unsigned)gw < WW);
                const float* xp = x + ((size_t)b * E + ch0 + cq * 8) * HWP + gh * WW + gw;
                float vv[8];
                float ss = 0.f;
                #pragma unroll
                for (int e = 0; e < 8; ++e) {
                    float v = ok ? xp[e * HWP] : 0.f;
                    vv[e] = v;
                    ss = fmaf(v, v, ss);
                }
                if (okc) {
                    half8 pk;
                    #pragma unroll
                    for (int e = 0; e < 8; ++e) pk[e] = (f16)vv[e];
                    *(half8*)&xs[r][cs][SWZ(cq, cs)] = pk;
                }
                ss += __shfl_xor(ss, 16);
                ss += __shfl_xor(ss, 32);
                if (cq == 0 && okc) ssqAcc[r][cs] += ss;
            }
        }
        __syncthreads();

        __builtin_amdgcn_s_setprio(1);
        #pragma unroll
        for (int tap = 0; tap < 9; ++tap) {
            int kh = tap / 3, kw = tap % 3;
            half8 A[4], Bf[4];
            #pragma unroll
            for (int mi = 0; mi < 4; ++mi) {
                int row = mi * 16 + lr;
                A[mi] = *(const half8*)&ws[tap][row][SWZ(ls, row)];
            }
            #pragma unroll
            for (int dh = 0; dh < 2; ++dh)
                #pragma unroll
                for (int wsg = 0; wsg < 2; ++wsg) {
                    int col = wv * 32 + wsg * 16 + lr + kw;
                    Bf[dh*2 + wsg] = *(const half8*)&xs[dh + kh][col][SWZ(ls, col)];
                }
            #pragma unroll
            for (int mi = 0; mi < 4; ++mi)
                #pragma unroll
                for (int ni = 0; ni < 4; ++ni)
                    acc[mi][ni] = __builtin_amdgcn_mfma_f32_16x16x32_f16(
                        A[mi], Bf[ni], acc[mi][ni], 0, 0, 0);
        }
        __builtin_amdgcn_s_setprio(0);
        __syncthreads();
    }

    if (!FAST && t < 64) winv[t] = rsqrtf(fmaxf(wSsq[t], 1e-24f));
    {
        int dh = t >> 7, w = t & 127;
        float S = 0.f;
        #pragma unroll
        for (int r = 0; r < 3; ++r)
            #pragma unroll
            for (int c = 0; c < 3; ++c)
                S += ssqAcc[dh + r][w + c];
        pinvL[dh][w] = rsqrtf(fmaxf(S, 1e-24f));
    }
    __syncthreads();

    int lq = lane >> 4;
    #pragma unroll
    for (int ni = 0; ni < 4; ++ni) {
        int dh = ni >> 1, wsg = ni & 1;
        int w = wv * 32 + wsg * 16 + lr;
        if (w >= WW) continue;
        float pv = pinvL[dh][w];
        int h = h0 + dh;
        #pragma unroll
        for (int mi = 0; mi < 4; ++mi) {
            #pragma unroll
            for (int rg = 0; rg < 4; ++rg) {
                int row = lq * 4 + rg;
                float s = acc[mi][ni][rg] * pv;
                if (!FAST) s *= winv[mi*16 + row];
                out[((size_t)(b * OO + o0 + mi*16 + row)) * HWP + h * WW + w] = s;
            }
        }
    }
}

extern "C" void kernel_launch(void* const* d_in, const int* in_sizes, int n_in,
                              void* d_out, int out_size, void* d_ws, size_t ws_size,
                              hipStream_t stream) {
    const float* x   = (const float*)d_in[0];
    const float* wgt = (const float*)d_in[1];
    float* out = (float*)d_out;

    const size_t pinv_bytes = (size_t)BB * HWP * sizeof(float);      // 401408
    const size_t wn_bytes   = (size_t)9 * OO * E * sizeof(f16);      // 589824
    if (ws_size >= pinv_bytes + wn_bytes && d_ws != nullptr) {
        float* pinv = (float*)d_ws;
        f16*   wn16 = (f16*)((char*)d_ws + pinv_bytes);
        wnorm16_kernel<<<OO, 128, 0, stream>>>(wgt, wn16);
        pinv_kernel<<<dim3(56, BB), 256, 0, stream>>>(x, pinv);
        cossim_cc16<<<1792, 256, 0, stream>>>(x, wn16, pinv, out);
    } else if (ws_size >= wn_bytes && d_ws != nullptr) {
        f16* wn16 = (f16*)d_ws;
        wnorm16_kernel<<<OO, 128, 0, stream>>>(wgt, wn16);
        cossim_mfma<1><<<dim3(56, 4, BB), 256, 0, stream>>>(x, wgt, wn16, out);
    } else {
        cossim_mfma<0><<<dim3(56, 4, BB), 256, 0, stream>>>(x, wgt, nullptr, out);
    }
}

// Round 9
// 117.395 us; speedup vs baseline: 5.3071x; 1.7511x over previous
//
#include <hip/hip_runtime.h>
#include <math.h>

#define BB 8
#define E  128
#define OO 256
#define HH 112
#define WW 112
#define HWP (HH*WW)   // 12544

typedef _Float16 f16;
typedef _Float16 half8 __attribute__((ext_vector_type(8)));
typedef float f32x4 __attribute__((ext_vector_type(4)));

// R4-proven swizzle for 64B-stride (32 f16) rows
#define SWZ(q, c) ((((q) + ((c) >> 1)) & 3) * 8)
// R8-proven swizzle for 32B-stride (16 f16) rows
#define SWZ16(oct, idx) ((((oct) ^ (((idx) >> 2) & 1))) * 8)

// ---------------- precompute 1: normalized f16 weights, layout [tap][o][ch]
__global__ __launch_bounds__(128)
void wnorm16_kernel(const float* __restrict__ wgt, f16* __restrict__ wn16) {
    int o = blockIdx.x;
    int c = threadIdx.x;
    const float* row = wgt + (size_t)o * 1152 + c * 9;
    float v[9];
    float ss = 0.f;
    #pragma unroll
    for (int tp = 0; tp < 9; ++tp) { v[tp] = row[tp]; ss = fmaf(v[tp], v[tp], ss); }
    ss += __shfl_xor(ss, 1);  ss += __shfl_xor(ss, 2);
    ss += __shfl_xor(ss, 4);  ss += __shfl_xor(ss, 8);
    ss += __shfl_xor(ss, 16); ss += __shfl_xor(ss, 32);
    __shared__ float r2[2];
    if ((c & 63) == 0) r2[c >> 6] = ss;
    __syncthreads();
    float inv = rsqrtf(fmaxf(r2[0] + r2[1], 1e-24f));
    #pragma unroll
    for (int tp = 0; tp < 9; ++tp)
        wn16[((size_t)tp * OO + o) * E + c] = (f16)(v[tp] * inv);
}

// ---------------- precompute 2a: x -> channel-last f16 xt[b][hw][c] + per-pixel ssq
__global__ __launch_bounds__(256)
void xcvt_kernel(const float* __restrict__ x, f16* __restrict__ xt,
                 float* __restrict__ ssq) {
    int blk = blockIdx.x;            // 0..391 (BB * HWP/256; HWP = 49*256)
    int b   = blk / 49;
    int hw  = (blk % 49) * 256 + threadIdx.x;
    const float* xb = x + (size_t)b * E * HWP + hw;
    f16* xo = xt + ((size_t)b * HWP + hw) * E;
    float s = 0.f;
    #pragma unroll 4
    for (int co = 0; co < 16; ++co) {
        half8 pk;
        #pragma unroll
        for (int e = 0; e < 8; ++e) {
            float v = xb[(size_t)(co * 8 + e) * HWP];   // coalesced across threads
            s = fmaf(v, v, s);
            pk[e] = (f16)v;
        }
        *(half8*)(xo + co * 8) = pk;
    }
    ssq[(size_t)b * HWP + hw] = s;
}

// ---------------- precompute 2b: 3x3 box-sum of ssq -> inverse patch norm
__global__ __launch_bounds__(256)
void boxinv2_kernel(const float* __restrict__ ssq, float* __restrict__ pinv) {
    int id = blockIdx.x * 256 + threadIdx.x;   // over B*HW
    int b = id / HWP;
    int hw = id % HWP;
    int h = hw / WW, w = hw % WW;
    const float* sb = ssq + (size_t)b * HWP;
    float S = 0.f;
    #pragma unroll
    for (int r = -1; r <= 1; ++r) {
        int hh = h + r;
        if ((unsigned)hh >= HH) continue;
        #pragma unroll
        for (int c = -1; c <= 1; ++c) {
            int ww = w + c;
            if ((unsigned)ww >= WW) continue;
            S += sb[hh * WW + ww];
        }
    }
    pinv[id] = rsqrtf(fmaxf(S, 1e-24f));
}

// ---------------- tier-A main: R8 cc16 structure + channel-last f16 x staging
// Block: 64 o x 2 h x 128 w; 4 waves; 16-ch chunks, tap-paired K=32, 4 blocks/CU.
__global__ __launch_bounds__(256, 4)
void cossim_xt(const f16* __restrict__ xt, const f16* __restrict__ wn16,
               const float* __restrict__ pinv, float* __restrict__ out) {
    int bid = blockIdx.x;        // XCD-aware: b = bid&7 -> one batch per XCD
    int b   = bid & 7;
    int j   = bid >> 3;
    int oy  = j / 56;
    int hp  = j % 56;
    int h0 = hp * 2;
    int o0 = oy * 64;
    int t    = threadIdx.x;
    int lane = t & 63;
    int wv   = t >> 6;

    __shared__ f16 ws[10][64][16];   // taps 0..8 staged; tap 9 stays zero
    __shared__ f16 xs[4][130][16];

    if (t < 128) {
        int o = t >> 1, oct = t & 1;
        *(half8*)&ws[9][o][oct * 8] = (half8)(f16)0.f;
    }

    f32x4 zero4 = {0.f, 0.f, 0.f, 0.f};
    f32x4 acc[4][4];
    #pragma unroll
    for (int mi = 0; mi < 4; ++mi)
        #pragma unroll
        for (int ni = 0; ni < 4; ++ni) acc[mi][ni] = zero4;

    const int lr = lane & 15;
    const int ls = lane >> 4;

    for (int ch0 = 0; ch0 < E; ch0 += 16) {
        // ---- stage W: 9 taps x 64 o x 2 octets = 1152 half8 copies (L2)
        #pragma unroll
        for (int k = 0; k < 5; ++k) {
            int i = t + k * 256;
            if (i < 1152) {
                int tap = i >> 7, rem = i & 127, o = rem >> 1, oct = rem & 1;
                half8 v = *(const half8*)(wn16 +
                    ((size_t)(tap * OO + o0 + o)) * E + ch0 + oct * 8);
                *(half8*)&ws[tap][o][SWZ16(oct, o)] = v;
            }
        }
        // ---- stage X: 1040 half8 loads from channel-last xt (coalesced 16B/lane)
        #pragma unroll
        for (int k = 0; k < 5; ++k) {
            int i = t + k * 256;
            if (i < 1040) {
                int r = i / 260, rem = i % 260, cs = rem >> 1, oct = rem & 1;
                int gh = h0 - 1 + r, gw = cs - 1;
                bool ok = ((unsigned)gh < HH) && ((unsigned)gw < WW);
                half8 pk = (half8)(f16)0.f;
                if (ok)
                    pk = *(const half8*)(xt +
                        ((size_t)b * HWP + gh * WW + gw) * E + ch0 + oct * 8);
                *(half8*)&xs[r][cs][SWZ16(oct, cs)] = pk;
            }
        }
        __syncthreads();

        // ---- MFMA: 5 tap-pairs x 16 mfma (pad pair uses zero ws[9])
        __builtin_amdgcn_s_setprio(1);
        #pragma unroll
        for (int p = 0; p < 5; ++p) {
            int tpl = 2 * p + (ls >> 1);
            int tpe = (tpl > 8) ? 0 : tpl;
            int kh  = tpe / 3;
            int kw  = tpe - 3 * kh;
            int oct = ls & 1;
            half8 A[4], Bf[4];
            #pragma unroll
            for (int mi = 0; mi < 4; ++mi) {
                int row = mi * 16 + lr;
                A[mi] = *(const half8*)&ws[tpl][row][SWZ16(oct, row)];
            }
            #pragma unroll
            for (int dh = 0; dh < 2; ++dh)
                #pragma unroll
                for (int wsg = 0; wsg < 2; ++wsg) {
                    int col = wv * 32 + wsg * 16 + lr + kw;
                    Bf[dh * 2 + wsg] = *(const half8*)&xs[dh + kh][col][SWZ16(oct, col)];
                }
            #pragma unroll
            for (int mi = 0; mi < 4; ++mi)
                #pragma unroll
                for (int ni = 0; ni < 4; ++ni)
                    acc[mi][ni] = __builtin_amdgcn_mfma_f32_16x16x32_f16(
                        A[mi], Bf[ni], acc[mi][ni], 0, 0, 0);
        }
        __builtin_amdgcn_s_setprio(0);
        __syncthreads();
    }

    // ---- epilogue: scale by pinv (weights pre-normalized)
    int lq = lane >> 4;
    #pragma unroll
    for (int ni = 0; ni < 4; ++ni) {
        int dh = ni >> 1, wsg = ni & 1;
        int w = wv * 32 + wsg * 16 + lr;
        if (w >= WW) continue;
        float pv = pinv[(size_t)b * HWP + (h0 + dh) * WW + w];
        int h = h0 + dh;
        #pragma unroll
        for (int mi = 0; mi < 4; ++mi) {
            #pragma unroll
            for (int rg = 0; rg < 4; ++rg) {
                int row = lq * 4 + rg;
                out[((size_t)(b * OO + o0 + mi * 16 + row)) * HWP + h * WW + w]
                    = acc[mi][ni][rg] * pv;
            }
        }
    }
}

// ---------------- fallback (R4-proven) main kernel
template<int FAST>
__global__ __launch_bounds__(256, 2)
void cossim_mfma(const float* __restrict__ x, const float* __restrict__ wgt,
                 const f16* __restrict__ wn16, float* __restrict__ out) {
    int hp = blockIdx.x;
    int oy = blockIdx.y;
    int b  = blockIdx.z;
    int h0 = hp * 2;
    int o0 = oy * 64;
    int t    = threadIdx.x;
    int lane = t & 63;
    int wv   = t >> 6;

    __shared__ f16   ws[9][64][32];
    __shared__ f16   xs[4][130][32];
    __shared__ float ssqAcc[4][130];
    __shared__ float wSsq[64];
    __shared__ float pinvL[2][128];
    __shared__ float winv[64];

    for (int i = t; i < 4*130 + 64; i += 256) {
        if (i < 4*130) ((float*)ssqAcc)[i] = 0.f;
        else wSsq[i - 4*130] = 0.f;
    }
    __syncthreads();

    f32x4 zero4 = {0.f, 0.f, 0.f, 0.f};
    f32x4 acc[4][4];
    #pragma unroll
    for (int mi = 0; mi < 4; ++mi)
        #pragma unroll
        for (int ni = 0; ni < 4; ++ni) acc[mi][ni] = zero4;

    const int lr = lane & 15;
    const int ls = lane >> 4;

    for (int ch0 = 0; ch0 < E; ch0 += 32) {
        if (FAST) {
            int o = t >> 2, q = t & 3;
            #pragma unroll
            for (int r = 0; r < 9; ++r) {
                half8 v = *(const half8*)(wn16 + ((size_t)(r * OO + o0 + o)) * E + ch0 + q * 8);
                *(half8*)&ws[r][o][SWZ(q, o)] = v;
            }
        } else {
            int o = t >> 2, q = t & 3;
            const float* wrow = wgt + (size_t)(o0 + o) * 1152 + ch0 * 9 + q * 72;
            float v[72];
            float ss = 0.f;
            #pragma unroll
            for (int i = 0; i < 18; ++i) {
                float4 f = ((const float4*)wrow)[i];
                v[i*4+0] = f.x; v[i*4+1] = f.y; v[i*4+2] = f.z; v[i*4+3] = f.w;
                ss = fmaf(f.x, f.x, ss); ss = fmaf(f.y, f.y, ss);
                ss = fmaf(f.z, f.z, ss); ss = fmaf(f.w, f.w, ss);
            }
            #pragma unroll
            for (int tp = 0; tp < 9; ++tp) {
                half8 pk;
                #pragma unroll
                for (int cl = 0; cl < 8; ++cl) pk[cl] = (f16)v[cl*9 + tp];
                *(half8*)&ws[tp][o][SWZ(q, o)] = pk;
            }
            ss += __shfl_xor(ss, 1);
            ss += __shfl_xor(ss, 2);
            if (q == 0) wSsq[o] += ss;
        }
        {
            int colL = lane & 15, cq = lane >> 4;
            #pragma unroll 2
            for (int it = 0; it < 9; ++it) {
                int g = it * 4 + wv;
                int r = g / 9, colb = g % 9;
                int cs = colb * 16 + colL;
                int gh = h0 - 1 + r;
                int gw = cs - 1;
                bool okc = (cs < 130);
                bool ok  = okc && ((unsigned)gh < HH) && ((unsigned)gw < WW);
                const float* xp = x + ((size_t)b * E + ch0 + cq * 8) * HWP + gh * WW + gw;
                float vv[8];
                float ss = 0.f;
                #pragma unroll
                for (int e = 0; e < 8; ++e) {
                    float v = ok ? xp[e * HWP] : 0.f;
                    vv[e] = v;
                    ss = fmaf(v, v, ss);
                }
                if (okc) {
                    half8 pk;
                    #pragma unroll
                    for (int e = 0; e < 8; ++e) pk[e] = (f16)vv[e];
                    *(half8*)&xs[r][cs][SWZ(cq, cs)] = pk;
                }
                ss += __shfl_xor(ss, 16);
                ss += __shfl_xor(ss, 32);
                if (cq == 0 && okc) ssqAcc[r][cs] += ss;
            }
        }
        __syncthreads();

        __builtin_amdgcn_s_setprio(1);
        #pragma unroll
        for (int tap = 0; tap < 9; ++tap) {
            int kh = tap / 3, kw = tap % 3;
            half8 A[4], Bf[4];
            #pragma unroll
            for (int mi = 0; mi < 4; ++mi) {
                int row = mi * 16 + lr;
                A[mi] = *(const half8*)&ws[tap][row][SWZ(ls, row)];
            }
            #pragma unroll
            for (int dh = 0; dh < 2; ++dh)
                #pragma unroll
                for (int wsg = 0; wsg < 2; ++wsg) {
                    int col = wv * 32 + wsg * 16 + lr + kw;
                    Bf[dh*2 + wsg] = *(const half8*)&xs[dh + kh][col][SWZ(ls, col)];
                }
            #pragma unroll
            for (int mi = 0; mi < 4; ++mi)
                #pragma unroll
                for (int ni = 0; ni < 4; ++ni)
                    acc[mi][ni] = __builtin_amdgcn_mfma_f32_16x16x32_f16(
                        A[mi], Bf[ni], acc[mi][ni], 0, 0, 0);
        }
        __builtin_amdgcn_s_setprio(0);
        __syncthreads();
    }

    if (!FAST && t < 64) winv[t] = rsqrtf(fmaxf(wSsq[t], 1e-24f));
    {
        int dh = t >> 7, w = t & 127;
        float S = 0.f;
        #pragma unroll
        for (int r = 0; r < 3; ++r)
            #pragma unroll
            for (int c = 0; c < 3; ++c)
                S += ssqAcc[dh + r][w + c];
        pinvL[dh][w] = rsqrtf(fmaxf(S, 1e-24f));
    }
    __syncthreads();

    int lq = lane >> 4;
    #pragma unroll
    for (int ni = 0; ni < 4; ++ni) {
        int dh = ni >> 1, wsg = ni & 1;
        int w = wv * 32 + wsg * 16 + lr;
        if (w >= WW) continue;
        float pv = pinvL[dh][w];
        int h = h0 + dh;
        #pragma unroll
        for (int mi = 0; mi < 4; ++mi) {
            #pragma unroll
            for (int rg = 0; rg < 4; ++rg) {
                int row = lq * 4 + rg;
                float s = acc[mi][ni][rg] * pv;
                if (!FAST) s *= winv[mi*16 + row];
                out[((size_t)(b * OO + o0 + mi*16 + row)) * HWP + h * WW + w] = s;
            }
        }
    }
}

extern "C" void kernel_launch(void* const* d_in, const int* in_sizes, int n_in,
                              void* d_out, int out_size, void* d_ws, size_t ws_size,
                              hipStream_t stream) {
    const float* x   = (const float*)d_in[0];
    const float* wgt = (const float*)d_in[1];
    float* out = (float*)d_out;

    const size_t xt_bytes   = (size_t)BB * HWP * E * sizeof(f16);    // 25,690,112
    const size_t ssq_bytes  = (size_t)BB * HWP * sizeof(float);      // 401,408
    const size_t pinv_bytes = (size_t)BB * HWP * sizeof(float);      // 401,408
    const size_t wn_bytes   = (size_t)9 * OO * E * sizeof(f16);      // 589,824
    const size_t need_A = xt_bytes + ssq_bytes + pinv_bytes + wn_bytes;

    if (ws_size >= need_A && d_ws != nullptr) {
        f16*   xtp  = (f16*)d_ws;
        float* ssq  = (float*)((char*)d_ws + xt_bytes);
        float* pinv = (float*)((char*)d_ws + xt_bytes + ssq_bytes);
        f16*   wn16 = (f16*)((char*)d_ws + xt_bytes + ssq_bytes + pinv_bytes);
        xcvt_kernel   <<<BB * (HWP / 256), 256, 0, stream>>>(x, xtp, ssq);
        wnorm16_kernel<<<OO, 128, 0, stream>>>(wgt, wn16);
        boxinv2_kernel<<<BB * (HWP / 256), 256, 0, stream>>>(ssq, pinv);
        cossim_xt     <<<1792, 256, 0, stream>>>(xtp, wn16, pinv, out);
    } else if (ws_size >= wn_bytes && d_ws != nullptr) {
        f16* wn16 = (f16*)d_ws;
        wnorm16_kernel<<<OO, 128, 0, stream>>>(wgt, wn16);
        cossim_mfma<1><<<dim3(56, 4, BB), 256, 0, stream>>>(x, wgt, wn16, out);
    } else {
        cossim_mfma<0><<<dim3(56, 4, BB), 256, 0, stream>>>(x, wgt, nullptr, out);
    }
}

// Round 10
// 89.214 us; speedup vs baseline: 6.9834x; 1.3159x over previous
//
#include <hip/hip_runtime.h>
#include <math.h>

#define BB 8
#define E  128
#define OO 256
#define HH 112
#define WW 112
#define HWP (HH*WW)   // 12544

typedef _Float16 f16;
typedef _Float16 half8 __attribute__((ext_vector_type(8)));
typedef float f32x4 __attribute__((ext_vector_type(4)));

// R4-proven swizzle for 64B-stride (32 f16) rows (fallback kernel)
#define SWZ(q, c) ((((q) + ((c) >> 1)) & 3) * 8)
// R8/R9-proven swizzle for 32B-stride (16 f16) rows
#define SWZ16(oct, idx) ((((oct) ^ (((idx) >> 2) & 1))) * 8)

// direct global->LDS DMA, 16B per lane; LDS dest is wave-uniform base + lane*16
__device__ __forceinline__ void load_lds16(const f16* g, f16* l) {
    __builtin_amdgcn_global_load_lds(
        (const __attribute__((address_space(1))) void*)g,
        (__attribute__((address_space(3))) void*)l, 16, 0, 0);
}

// ---------------- precompute 1 (tier-A): normalized f16 weights, [tap][cg][o][16] + zero page
__global__ __launch_bounds__(128)
void wnorm16b_kernel(const float* __restrict__ wgt, f16* __restrict__ wng,
                     float* __restrict__ zp) {
    if (blockIdx.x == 0 && threadIdx.x < 64) zp[threadIdx.x] = 0.f;   // 256B zero page
    int o = blockIdx.x;
    int c = threadIdx.x;
    const float* row = wgt + (size_t)o * 1152 + c * 9;
    float v[9];
    float ss = 0.f;
    #pragma unroll
    for (int tp = 0; tp < 9; ++tp) { v[tp] = row[tp]; ss = fmaf(v[tp], v[tp], ss); }
    ss += __shfl_xor(ss, 1);  ss += __shfl_xor(ss, 2);
    ss += __shfl_xor(ss, 4);  ss += __shfl_xor(ss, 8);
    ss += __shfl_xor(ss, 16); ss += __shfl_xor(ss, 32);
    __shared__ float r2[2];
    if ((c & 63) == 0) r2[c >> 6] = ss;
    __syncthreads();
    float inv = rsqrtf(fmaxf(r2[0] + r2[1], 1e-24f));
    int cg = c >> 4, ci = c & 15;
    #pragma unroll
    for (int tp = 0; tp < 9; ++tp)
        wng[(size_t)(tp * 8 + cg) * 4096 + o * 16 + ci] = (f16)(v[tp] * inv);
}

// ---------------- precompute 1 (fallback): normalized f16 weights, [tap][o][ch]
__global__ __launch_bounds__(128)
void wnorm16_kernel(const float* __restrict__ wgt, f16* __restrict__ wn16) {
    int o = blockIdx.x;
    int c = threadIdx.x;
    const float* row = wgt + (size_t)o * 1152 + c * 9;
    float v[9];
    float ss = 0.f;
    #pragma unroll
    for (int tp = 0; tp < 9; ++tp) { v[tp] = row[tp]; ss = fmaf(v[tp], v[tp], ss); }
    ss += __shfl_xor(ss, 1);  ss += __shfl_xor(ss, 2);
    ss += __shfl_xor(ss, 4);  ss += __shfl_xor(ss, 8);
    ss += __shfl_xor(ss, 16); ss += __shfl_xor(ss, 32);
    __shared__ float r2[2];
    if ((c & 63) == 0) r2[c >> 6] = ss;
    __syncthreads();
    float inv = rsqrtf(fmaxf(r2[0] + r2[1], 1e-24f));
    #pragma unroll
    for (int tp = 0; tp < 9; ++tp)
        wn16[((size_t)tp * OO + o) * E + c] = (f16)(v[tp] * inv);
}

// ---------------- precompute 2a: x -> f16 xt[b][cg][hw][16] + per-pixel ssq
__global__ __launch_bounds__(256)
void xcvt2_kernel(const float* __restrict__ x, f16* __restrict__ xtg,
                  float* __restrict__ ssq) {
    int blk = blockIdx.x;            // BB*49 blocks
    int b   = blk / 49;
    int hw  = (blk % 49) * 256 + threadIdx.x;
    const float* xb = x + (size_t)b * E * HWP + hw;
    float s = 0.f;
    #pragma unroll
    for (int cg = 0; cg < 8; ++cg) {
        half8 p0, p1;
        #pragma unroll
        for (int e = 0; e < 8; ++e) {
            float v = xb[(size_t)(cg * 16 + e) * HWP];
            s = fmaf(v, v, s); p0[e] = (f16)v;
        }
        #pragma unroll
        for (int e = 0; e < 8; ++e) {
            float v = xb[(size_t)(cg * 16 + 8 + e) * HWP];
            s = fmaf(v, v, s); p1[e] = (f16)v;
        }
        f16* o = xtg + ((size_t)(b * 8 + cg) * HWP + hw) * 16;
        *(half8*)o = p0;
        *(half8*)(o + 8) = p1;
    }
    ssq[(size_t)b * HWP + hw] = s;
}

// ---------------- precompute 2b: 3x3 box-sum of ssq -> inverse patch norm
__global__ __launch_bounds__(256)
void boxinv2_kernel(const float* __restrict__ ssq, float* __restrict__ pinv) {
    int id = blockIdx.x * 256 + threadIdx.x;
    int b = id / HWP;
    int hw = id % HWP;
    int h = hw / WW, w = hw % WW;
    const float* sb = ssq + (size_t)b * HWP;
    float S = 0.f;
    #pragma unroll
    for (int r = -1; r <= 1; ++r) {
        int hh = h + r;
        if ((unsigned)hh >= HH) continue;
        #pragma unroll
        for (int c = -1; c <= 1; ++c) {
            int ww = w + c;
            if ((unsigned)ww >= WW) continue;
            S += sb[hh * WW + ww];
        }
    }
    pinv[id] = rsqrtf(fmaxf(S, 1e-24f));
}

// ---------------- tier-A main: 2-phase pipelined (global_load_lds + dbuf + counted vmcnt)
// Block: 64 o x 2 h x 128 w; 4 waves; 16-ch chunks, tap-paired K=32 (R9 math).
// LDS layouts are byte-identical to R9 (conflicts measured 0); staging sources
// are pre-swizzled so linear gload_lds lands data in the swizzled slots.
__global__ __launch_bounds__(256, 2)
void cossim_pipe2(const f16* __restrict__ xtg, const f16* __restrict__ wng,
                  const float* __restrict__ pinv, const f16* __restrict__ zp,
                  float* __restrict__ out) {
    int bid = blockIdx.x;        // XCD-aware: b = bid&7
    int b   = bid & 7;
    int j2  = bid >> 3;
    int oy  = j2 / 56;
    int hp  = j2 % 56;
    int h0 = hp * 2;
    int o0 = oy * 64;
    int t    = threadIdx.x;
    int lane = t & 63;
    int wv   = t >> 6;

    __shared__ f16 xsb[2][8704];    // 1088 slots x 16B per buffer (1040 used + pad)
    __shared__ f16 wsb[2][10240];   // 1280 slots (1152 staged + 128 zero tap9)
    __shared__ f16 scr[512];        // dummy-DMA landing zone

    // zero pad-tap9 slots in both buffers (read every chunk, never staged)
    if (t < 128) {
        uint4 z = {0u, 0u, 0u, 0u};
        *(uint4*)&wsb[0][(1152 + t) * 8] = z;
        *(uint4*)&wsb[1][(1152 + t) * 8] = z;
    }

    // per-lane staging source offsets (chunk-invariant parts)
    int xoffk[5], woffk[5];
    #pragma unroll
    for (int k = 0; k < 5; ++k) {
        int jj = k * 4 + wv;
        int xo = -1;
        if (jj <= 16) {
            int s = jj * 64 + lane;
            if (s < 1040) {
                int po = s & 1, csm = s >> 1;
                int r = csm / 130, cs = csm - r * 130;
                int oct = po ^ ((cs >> 2) & 1);      // inverse of SWZ16
                int gh = h0 - 1 + r, gw = cs - 1;
                if ((unsigned)gh < (unsigned)HH && (unsigned)gw < (unsigned)WW)
                    xo = (gh * WW + gw) * 16 + oct * 8;
            }
        }
        xoffk[k] = xo;
        int uu = k * 4 + wv;
        int wo = -1;
        if (uu < 18) {
            int s = uu * 64 + lane;
            int tap = s >> 7, rem = s & 127, o = rem >> 1, po = rem & 1;
            int oct = po ^ ((o >> 2) & 1);
            wo = tap * 32768 + (o0 + o) * 16 + oct * 8;
        }
        woffk[k] = wo;
    }

    f32x4 acc[4][4];
    #pragma unroll
    for (int mi = 0; mi < 4; ++mi)
        #pragma unroll
        for (int ni = 0; ni < 4; ++ni) acc[mi][ni] = (f32x4){0.f, 0.f, 0.f, 0.f};

    const int lr = lane & 15;
    const int ls = lane >> 4;
    const f16* xb8 = xtg + (size_t)b * 8 * HWP * 16;

    __syncthreads();   // tap9 zeros visible before first MFMA

#define STAGE(CG, BUF) do {                                                     \
    const f16* xpl_ = xb8 + (size_t)(CG) * (HWP * 16);                          \
    const f16* wpl_ = wng + (CG) * 4096;                                        \
    _Pragma("unroll")                                                           \
    for (int k_ = 0; k_ < 5; ++k_) {                                            \
        int jj_ = k_ * 4 + wv;                                                  \
        f16* dst_ = (jj_ <= 16) ? &xsb[BUF][jj_ * 512] : scr;                   \
        const f16* src_ = (jj_ <= 16 && xoffk[k_] >= 0) ? (xpl_ + xoffk[k_])    \
                                                        : zp;                   \
        load_lds16(src_, dst_);                                                 \
    }                                                                           \
    _Pragma("unroll")                                                           \
    for (int k_ = 0; k_ < 5; ++k_) {                                            \
        int uu_ = k_ * 4 + wv;                                                  \
        f16* dst_ = (uu_ < 18) ? &wsb[BUF][uu_ * 512] : scr;                    \
        const f16* src_ = (uu_ < 18) ? (wpl_ + woffk[k_]) : zp;                 \
        load_lds16(src_, dst_);                                                 \
    }                                                                           \
} while (0)

#define PIPE_BAR() do {                                                         \
    __builtin_amdgcn_sched_barrier(0);                                          \
    __builtin_amdgcn_s_barrier();                                               \
    __builtin_amdgcn_sched_barrier(0);                                          \
} while (0)

#define MFMAP(BUF) do {                                                         \
    __builtin_amdgcn_s_setprio(1);                                              \
    _Pragma("unroll")                                                           \
    for (int p = 0; p < 5; ++p) {                                               \
        int tpl = 2 * p + (ls >> 1);                                            \
        int tpe = (tpl > 8) ? 0 : tpl;                                          \
        int kh = tpe / 3, kw = tpe - 3 * kh;                                    \
        int oct = ls & 1;                                                       \
        half8 A[4], Bf[4];                                                      \
        _Pragma("unroll")                                                       \
        for (int mi = 0; mi < 4; ++mi) {                                        \
            int row = mi * 16 + lr;                                             \
            A[mi] = *(const half8*)&wsb[BUF][                                   \
                (tpl * 128 + row * 2 + (oct ^ ((row >> 2) & 1))) * 8];          \
        }                                                                       \
        _Pragma("unroll")                                                       \
        for (int dh = 0; dh < 2; ++dh)                                          \
            _Pragma("unroll")                                                   \
            for (int wsg = 0; wsg < 2; ++wsg) {                                 \
                int col = wv * 32 + wsg * 16 + lr + kw;                         \
                Bf[dh * 2 + wsg] = *(const half8*)&xsb[BUF][                    \
                    ((dh + kh) * 260 + col * 2 + (oct ^ ((col >> 2) & 1))) * 8];\
            }                                                                   \
        _Pragma("unroll")                                                       \
        for (int mi = 0; mi < 4; ++mi)                                          \
            _Pragma("unroll")                                                   \
            for (int ni = 0; ni < 4; ++ni)                                      \
                acc[mi][ni] = __builtin_amdgcn_mfma_f32_16x16x32_f16(           \
                    A[mi], Bf[ni], acc[mi][ni], 0, 0, 0);                       \
    }                                                                           \
    __builtin_amdgcn_s_setprio(0);                                              \
} while (0)

#define ITER_MID(C) do {                                                        \
    STAGE((C) + 1, ((C) + 1) & 1);                                              \
    asm volatile("s_waitcnt vmcnt(10)" ::: "memory");                           \
    PIPE_BAR();                                                                 \
    MFMAP((C) & 1);                                                             \
    PIPE_BAR();                                                                 \
} while (0)

    STAGE(0, 0);
    ITER_MID(0);
    ITER_MID(1);
    ITER_MID(2);
    ITER_MID(3);
    ITER_MID(4);
    ITER_MID(5);
    ITER_MID(6);
    asm volatile("s_waitcnt vmcnt(0)" ::: "memory");
    PIPE_BAR();
    MFMAP(1);

#undef STAGE
#undef PIPE_BAR
#undef MFMAP
#undef ITER_MID

    // epilogue: scale by pinv (weights pre-normalized)
    int lq = lane >> 4;
    #pragma unroll
    for (int ni = 0; ni < 4; ++ni) {
        int dh = ni >> 1, wsg = ni & 1;
        int w = wv * 32 + wsg * 16 + lr;
        if (w >= WW) continue;
        float pv = pinv[(size_t)b * HWP + (h0 + dh) * WW + w];
        int h = h0 + dh;
        #pragma unroll
        for (int mi = 0; mi < 4; ++mi) {
            #pragma unroll
            for (int rg = 0; rg < 4; ++rg) {
                int row = lq * 4 + rg;
                out[((size_t)(b * OO + o0 + mi * 16 + row)) * HWP + h * WW + w]
                    = acc[mi][ni][rg] * pv;
            }
        }
    }
}

// ---------------- fallback (R4-proven) main kernel
template<int FAST>
__global__ __launch_bounds__(256, 2)
void cossim_mfma(const float* __restrict__ x, const float* __restrict__ wgt,
                 const f16* __restrict__ wn16, float* __restrict__ out) {
    int hp = blockIdx.x;
    int oy = blockIdx.y;
    int b  = blockIdx.z;
    int h0 = hp * 2;
    int o0 = oy * 64;
    int t    = threadIdx.x;
    int lane = t & 63;
    int wv   = t >> 6;

    __shared__ f16   ws[9][64][32];
    __shared__ f16   xs[4][130][32];
    __shared__ float ssqAcc[4][130];
    __shared__ float wSsq[64];
    __shared__ float pinvL[2][128];
    __shared__ float winv[64];

    for (int i = t; i < 4*130 + 64; i += 256) {
        if (i < 4*130) ((float*)ssqAcc)[i] = 0.f;
        else wSsq[i - 4*130] = 0.f;
    }
    __syncthreads();

    f32x4 zero4 = {0.f, 0.f, 0.f, 0.f};
    f32x4 acc[4][4];
    #pragma unroll
    for (int mi = 0; mi < 4; ++mi)
        #pragma unroll
        for (int ni = 0; ni < 4; ++ni) acc[mi][ni] = zero4;

    const int lr = lane & 15;
    const int ls = lane >> 4;

    for (int ch0 = 0; ch0 < E; ch0 += 32) {
        if (FAST) {
            int o = t >> 2, q = t & 3;
            #pragma unroll
            for (int r = 0; r < 9; ++r) {
                half8 v = *(const half8*)(wn16 + ((size_t)(r * OO + o0 + o)) * E + ch0 + q * 8);
                *(half8*)&ws[r][o][SWZ(q, o)] = v;
            }
        } else {
            int o = t >> 2, q = t & 3;
            const float* wrow = wgt + (size_t)(o0 + o) * 1152 + ch0 * 9 + q * 72;
            float v[72];
            float ss = 0.f;
            #pragma unroll
            for (int i = 0; i < 18; ++i) {
                float4 f = ((const float4*)wrow)[i];
                v[i*4+0] = f.x; v[i*4+1] = f.y; v[i*4+2] = f.z; v[i*4+3] = f.w;
                ss = fmaf(f.x, f.x, ss); ss = fmaf(f.y, f.y, ss);
                ss = fmaf(f.z, f.z, ss); ss = fmaf(f.w, f.w, ss);
            }
            #pragma unroll
            for (int tp = 0; tp < 9; ++tp) {
                half8 pk;
                #pragma unroll
                for (int cl = 0; cl < 8; ++cl) pk[cl] = (f16)v[cl*9 + tp];
                *(half8*)&ws[tp][o][SWZ(q, o)] = pk;
            }
            ss += __shfl_xor(ss, 1);
            ss += __shfl_xor(ss, 2);
            if (q == 0) wSsq[o] += ss;
        }
        {
            int colL = lane & 15, cq = lane >> 4;
            #pragma unroll 2
            for (int it = 0; it < 9; ++it) {
                int g = it * 4 + wv;
                int r = g / 9, colb = g % 9;
                int cs = colb * 16 + colL;
                int gh = h0 - 1 + r;
                int gw = cs - 1;
                bool okc = (cs < 130);
                bool ok  = okc && ((unsigned)gh < HH) && ((unsigned)gw < WW);
                const float* xp = x + ((size_t)b * E + ch0 + cq * 8) * HWP + gh * WW + gw;
                float vv[8];
                float ss = 0.f;
                #pragma unroll
                for (int e = 0; e < 8; ++e) {
                    float v = ok ? xp[e * HWP] : 0.f;
                    vv[e] = v;
                    ss = fmaf(v, v, ss);
                }
                if (okc) {
                    half8 pk;
                    #pragma unroll
                    for (int e = 0; e < 8; ++e) pk[e] = (f16)vv[e];
                    *(half8*)&xs[r][cs][SWZ(cq, cs)] = pk;
                }
                ss += __shfl_xor(ss, 16);
                ss += __shfl_xor(ss, 32);
                if (cq == 0 && okc) ssqAcc[r][cs] += ss;
            }
        }
        __syncthreads();

        __builtin_amdgcn_s_setprio(1);
        #pragma unroll
        for (int tap = 0; tap < 9; ++tap) {
            int kh = tap / 3, kw = tap % 3;
            half8 A[4], Bf[4];
            #pragma unroll
            for (int mi = 0; mi < 4; ++mi) {
                int row = mi * 16 + lr;
                A[mi] = *(const half8*)&ws[tap][row][SWZ(ls, row)];
            }
            #pragma unroll
            for (int dh = 0; dh < 2; ++dh)
                #pragma unroll
                for (int wsg = 0; wsg < 2; ++wsg) {
                    int col = wv * 32 + wsg * 16 + lr + kw;
                    Bf[dh*2 + wsg] = *(const half8*)&xs[dh + kh][col][SWZ(ls, col)];
                }
            #pragma unroll
            for (int mi = 0; mi < 4; ++mi)
                #pragma unroll
                for (int ni = 0; ni < 4; ++ni)
                    acc[mi][ni] = __builtin_amdgcn_mfma_f32_16x16x32_f16(
                        A[mi], Bf[ni], acc[mi][ni], 0, 0, 0);
        }
        __builtin_amdgcn_s_setprio(0);
        __syncthreads();
    }

    if (!FAST && t < 64) winv[t] = rsqrtf(fmaxf(wSsq[t], 1e-24f));
    {
        int dh = t >> 7, w = t & 127;
        float S = 0.f;
        #pragma unroll
        for (int r = 0; r < 3; ++r)
            #pragma unroll
            for (int c = 0; c < 3; ++c)
                S += ssqAcc[dh + r][w + c];
        pinvL[dh][w] = rsqrtf(fmaxf(S, 1e-24f));
    }
    __syncthreads();

    int lq = lane >> 4;
    #pragma unroll
    for (int ni = 0; ni < 4; ++ni) {
        int dh = ni >> 1, wsg = ni & 1;
        int w = wv * 32 + wsg * 16 + lr;
        if (w >= WW) continue;
        float pv = pinvL[dh][w];
        int h = h0 + dh;
        #pragma unroll
        for (int mi = 0; mi < 4; ++mi) {
            #pragma unroll
            for (int rg = 0; rg < 4; ++rg) {
                int row = lq * 4 + rg;
                float s = acc[mi][ni][rg] * pv;
                if (!FAST) s *= winv[mi*16 + row];
                out[((size_t)(b * OO + o0 + mi*16 + row)) * HWP + h * WW + w] = s;
            }
        }
    }
}

extern "C" void kernel_launch(void* const* d_in, const int* in_sizes, int n_in,
                              void* d_out, int out_size, void* d_ws, size_t ws_size,
                              hipStream_t stream) {
    const float* x   = (const float*)d_in[0];
    const float* wgt = (const float*)d_in[1];
    float* out = (float*)d_out;

    const size_t zp_b   = 1024;
    const size_t xt_b   = (size_t)BB * 8 * HWP * 16 * sizeof(f16);   // 25,690,112
    const size_t ssq_b  = (size_t)BB * HWP * sizeof(float);          // 401,408
    const size_t pinv_b = (size_t)BB * HWP * sizeof(float);          // 401,408
    const size_t wng_b  = (size_t)9 * 8 * 4096 * sizeof(f16);        // 589,824
    const size_t need_A = zp_b + xt_b + ssq_b + pinv_b + wng_b;      // 27,083,776
    const size_t wn_bytes = (size_t)9 * OO * E * sizeof(f16);        // 589,824 (fallback)

    if (ws_size >= need_A && d_ws != nullptr) {
        f16*   zp   = (f16*)d_ws;
        f16*   xtg  = (f16*)((char*)d_ws + zp_b);
        float* ssq  = (float*)((char*)d_ws + zp_b + xt_b);
        float* pinv = (float*)((char*)d_ws + zp_b + xt_b + ssq_b);
        f16*   wng  = (f16*)((char*)d_ws + zp_b + xt_b + ssq_b + pinv_b);
        xcvt2_kernel   <<<BB * (HWP / 256), 256, 0, stream>>>(x, xtg, ssq);
        wnorm16b_kernel<<<OO, 128, 0, stream>>>(wgt, wng, (float*)zp);
        boxinv2_kernel <<<BB * (HWP / 256), 256, 0, stream>>>(ssq, pinv);
        cossim_pipe2   <<<1792, 256, 0, stream>>>(xtg, wng, pinv, zp, out);
    } else if (ws_size >= wn_bytes && d_ws != nullptr) {
        f16* wn16 = (f16*)d_ws;
        wnorm16_kernel<<<OO, 128, 0, stream>>>(wgt, wn16);
        cossim_mfma<1><<<dim3(56, 4, BB), 256, 0, stream>>>(x, wgt, wn16, out);
    } else {
        cossim_mfma<0><<<dim3(56, 4, BB), 256, 0, stream>>>(x, wgt, nullptr, out);
    }
}